// Round 1
// baseline (328.079 us; speedup 1.0000x reference)
//
#include <hip/hip_runtime.h>

#define T_TOK 16384
#define DM 1024
#define DFF 4096
#define NE 8
#define CAP 320
#define RP 384   // per-expert padded rows (3 x 128 tiles)

typedef __attribute__((ext_vector_type(8))) short bf16x8;
typedef __attribute__((ext_vector_type(4))) float f32x4;

__device__ __forceinline__ unsigned short f2bf(float f) {
    unsigned int u = __builtin_bit_cast(unsigned int, f);
    u += 0x7FFFu + ((u >> 16) & 1u);   // round-to-nearest-even (finite inputs)
    return (unsigned short)(u >> 16);
}

__device__ __forceinline__ void store_out(unsigned short* p, float v) { *p = f2bf(v); }
__device__ __forceinline__ void store_out(float* p, float v) { *p = v; }

// ---------------- init ----------------
__global__ void k_init(float* sumprob) {
    if (threadIdx.x < NE) sumprob[threadIdx.x] = 0.f;
}

// ---------------- router: logits, softmax, argmax, prob sums ----------------
__global__ __launch_bounds__(256) void k_router(
    const float* __restrict__ x, const float* __restrict__ rw,
    const float* __restrict__ rb, int* __restrict__ eidx,
    float* __restrict__ sumprob)
{
    __shared__ float w[DM * NE];
    for (int i = threadIdx.x; i < DM * NE; i += 256) w[i] = rw[i];
    __syncthreads();

    int t = blockIdx.x * 256 + threadIdx.x;
    float a[NE];
    #pragma unroll
    for (int e = 0; e < NE; ++e) a[e] = rb[e];

    const float4* xr = reinterpret_cast<const float4*>(x + (size_t)t * DM);
    for (int kk = 0; kk < DM / 4; ++kk) {
        float4 xv = xr[kk];
        #pragma unroll
        for (int c = 0; c < 4; ++c) {
            float xs = (c == 0) ? xv.x : (c == 1) ? xv.y : (c == 2) ? xv.z : xv.w;
            const float4* wr = reinterpret_cast<const float4*>(&w[(kk * 4 + c) * NE]);
            float4 w0 = wr[0], w1 = wr[1];
            a[0] += xs * w0.x; a[1] += xs * w0.y; a[2] += xs * w0.z; a[3] += xs * w0.w;
            a[4] += xs * w1.x; a[5] += xs * w1.y; a[6] += xs * w1.z; a[7] += xs * w1.w;
        }
    }

    // argmax (first occurrence of max, matches jnp.argmax)
    float m = a[0]; int bi = 0;
    #pragma unroll
    for (int e = 1; e < NE; ++e) if (a[e] > m) { m = a[e]; bi = e; }

    float p[NE], s = 0.f;
    #pragma unroll
    for (int e = 0; e < NE; ++e) { p[e] = __expf(a[e] - m); s += p[e]; }
    float inv = 1.f / s;
    eidx[t] = bi;

    #pragma unroll
    for (int e = 0; e < NE; ++e) {
        float v = p[e] * inv;
        #pragma unroll
        for (int o = 32; o > 0; o >>= 1) v += __shfl_down(v, o);
        if ((threadIdx.x & 63) == 0) atomicAdd(&sumprob[e], v);
    }
}

// ---------------- per-expert sequential rank scan ----------------
__global__ __launch_bounds__(256) void k_scan(
    const int* __restrict__ eidx, int* __restrict__ token_slot,
    int* __restrict__ s2t, int* __restrict__ counts)
{
    const int e = blockIdx.x;
    const int tid = threadIdx.x, lane = tid & 63, w = tid >> 6;
    __shared__ int wts[4];

    for (int i = tid; i < CAP; i += 256) s2t[e * CAP + i] = -1;
    __syncthreads();

    int running = 0;
    for (int base = 0; base < T_TOK; base += 256) {
        int t = base + tid;
        bool flag = (eidx[t] == e);
        unsigned long long mask = __ballot(flag);
        int wp = __popcll(mask & ((1ull << lane) - 1ull));
        if (lane == 0) wts[w] = __popcll(mask);
        __syncthreads();
        int woff = 0, btot = 0;
        #pragma unroll
        for (int j = 0; j < 4; ++j) { int v = wts[j]; btot += v; if (j < w) woff += v; }
        if (flag) {
            int rank = running + woff + wp;
            if (rank < CAP) {
                token_slot[t] = e * CAP + rank;
                s2t[e * CAP + rank] = t;
            } else {
                token_slot[t] = -1;
            }
        }
        running += btot;
        __syncthreads();
    }
    if (tid == 0) counts[e] = running;
}

// ---------------- load-balance loss ----------------
__global__ void k_lb(const int* __restrict__ counts, const float* __restrict__ sumprob,
                     float* __restrict__ out_lb)
{
    if (threadIdx.x == 0) {
        float acc = 0.f;
        for (int e = 0; e < NE; ++e) acc += (float)counts[e] * sumprob[e];
        *out_lb = (float)NE * acc / ((float)T_TOK * (float)T_TOK);
    }
}

// ---------------- gather kept tokens -> bf16 buffer (zero padding rows) ----------------
__global__ __launch_bounds__(256) void k_gather(
    const float* __restrict__ x, const int* __restrict__ s2t,
    unsigned short* __restrict__ xb)
{
    int r = blockIdx.x;               // 0 .. NE*RP-1
    int e = r / RP, i = r - e * RP;
    int tok = (i < CAP) ? s2t[e * CAP + i] : -1;
    int tid = threadIdx.x;
    unsigned short* dst = xb + (size_t)r * DM + tid * 4;
    if (tok >= 0) {
        float4 v = reinterpret_cast<const float4*>(x + (size_t)tok * DM)[tid];
        short4 b = make_short4((short)f2bf(v.x), (short)f2bf(v.y),
                               (short)f2bf(v.z), (short)f2bf(v.w));
        *reinterpret_cast<short4*>(dst) = b;
    } else {
        *reinterpret_cast<short4*>(dst) = make_short4(0, 0, 0, 0);
    }
}

// ---------------- grouped GEMM: C[e] = act(A[e] @ B[e] + bias[e]) ----------------
// A: bf16 [NE][RP][K] row-major. B: f32 [NE][K][N] row-major (converted to bf16
// during LDS staging). 4 waves in 2x2; each wave owns (MF*16)x(NF*16) output.
// MFMA 16x16x32 bf16: A-frag lane: row=lane&15, k=8*(lane>>4)+j
//                     C/D:        col=lane&15, row=4*(lane>>4)+i   (guide-verified)
template<int MF, int NF, bool RELU, typename OutT>
__global__ __launch_bounds__(256) void k_gemm(
    const unsigned short* __restrict__ A, const float* __restrict__ B,
    const float* __restrict__ bias, OutT* __restrict__ C,
    int K, int N)
{
    constexpr int BM = 2 * MF * 16;
    constexpr int BN = 2 * NF * 16;
    constexpr int CA = (4 * BM) / 256;   // A chunks (bf16x8) per thread
    constexpr int CB = (4 * BN) / 256;   // B (kgrp,col) pairs per thread

    __shared__ bf16x8 lA[4][BM];   // [kgrp][row] -> 8 k-contiguous bf16
    __shared__ bf16x8 lB[4][BN];   // [kgrp][col]

    const int e  = blockIdx.z;
    const int m0 = blockIdx.y * BM;
    const int n0 = blockIdx.x * BN;
    const int tid = threadIdx.x, lane = tid & 63;
    const int w = tid >> 6, wm = w >> 1, wn = w & 1;
    const int lrow = lane & 15, kg = lane >> 4;

    const unsigned short* Ae = A + (size_t)e * RP * K;
    const float* Be = B + (size_t)e * K * N;

    f32x4 acc[MF][NF] = {};

    for (int k0 = 0; k0 < K; k0 += 32) {
        __syncthreads();
        // stage A (already bf16): 16B per chunk, coalesced 64B per 4 lanes
        #pragma unroll
        for (int c = 0; c < CA; ++c) {
            int idx = tid + c * 256;
            int q = idx & 3, row = idx >> 2;
            lA[q][row] = *reinterpret_cast<const bf16x8*>(
                Ae + (size_t)(m0 + row) * K + k0 + q * 8);
        }
        // stage B: 8 strided f32 loads (lane-coalesced in col), convert, one b128 write
        #pragma unroll
        for (int c = 0; c < CB; ++c) {
            int idx = tid + c * 256;
            int col = idx & (BN - 1), q = idx / BN;
            const float* bp = Be + (size_t)(k0 + q * 8) * N + n0 + col;
            bf16x8 v;
            #pragma unroll
            for (int j = 0; j < 8; ++j) v[j] = (short)f2bf(bp[(size_t)j * N]);
            lB[q][col] = v;
        }
        __syncthreads();

        bf16x8 af[MF], bfr[NF];
        #pragma unroll
        for (int m = 0; m < MF; ++m) af[m] = lA[kg][wm * MF * 16 + m * 16 + lrow];
        #pragma unroll
        for (int n = 0; n < NF; ++n) bfr[n] = lB[kg][wn * NF * 16 + n * 16 + lrow];
        #pragma unroll
        for (int m = 0; m < MF; ++m)
            #pragma unroll
            for (int n = 0; n < NF; ++n)
                acc[m][n] = __builtin_amdgcn_mfma_f32_16x16x32_bf16(
                    af[m], bfr[n], acc[m][n], 0, 0, 0);
    }

    #pragma unroll
    for (int n = 0; n < NF; ++n) {
        int col = n0 + wn * NF * 16 + n * 16 + lrow;
        float bv = bias[e * N + col];
        #pragma unroll
        for (int m = 0; m < MF; ++m) {
            int rbase = m0 + wm * MF * 16 + m * 16 + kg * 4;
            #pragma unroll
            for (int i = 0; i < 4; ++i) {
                float v = acc[m][n][i] + bv;
                if (RELU) v = fmaxf(v, 0.f);
                store_out(C + ((size_t)e * RP + rbase + i) * (size_t)N + col, v);
            }
        }
    }
}

// ---------------- scatter back (zeros for dropped) ----------------
__global__ __launch_bounds__(256) void k_scatter(
    const float* __restrict__ y, const int* __restrict__ token_slot,
    float* __restrict__ out)
{
    int t = blockIdx.x;
    int slot = token_slot[t];
    float4* o = reinterpret_cast<float4*>(out + (size_t)t * DM);
    if (slot >= 0) {
        int e = slot / CAP, i = slot - e * CAP;
        o[threadIdx.x] = reinterpret_cast<const float4*>(
            y + ((size_t)e * RP + i) * DM)[threadIdx.x];
    } else {
        o[threadIdx.x] = make_float4(0.f, 0.f, 0.f, 0.f);
    }
}

extern "C" void kernel_launch(void* const* d_in, const int* in_sizes, int n_in,
                              void* d_out, int out_size, void* d_ws, size_t ws_size,
                              hipStream_t stream)
{
    const float* x  = (const float*)d_in[0];
    const float* rw = (const float*)d_in[1];
    const float* rb = (const float*)d_in[2];
    const float* w1 = (const float*)d_in[3];
    const float* b1 = (const float*)d_in[4];
    const float* w2 = (const float*)d_in[5];
    const float* b2 = (const float*)d_in[6];
    float* out = (float*)d_out;

    char* ws = (char*)d_ws;
    int*   eidx       = (int*)(ws);                        // 16384 int
    int*   token_slot = (int*)(ws + 65536);                // 16384 int
    int*   s2t        = (int*)(ws + 131072);               // 2560 int
    int*   counts     = (int*)(ws + 141312);               // 8 int
    float* sumprob    = (float*)(ws + 141376);             // 8 f32
    unsigned short* xb = (unsigned short*)(ws + 147456);                       // [NE][RP][DM] bf16
    unsigned short* h  = (unsigned short*)(ws + 147456 + 6291456);             // [NE][RP][DFF] bf16
    float*          y  = (float*)(ws + 147456 + 6291456 + 25165824);           // [NE][RP][DM] f32

    hipLaunchKernelGGL(k_init, dim3(1), dim3(64), 0, stream, sumprob);
    hipLaunchKernelGGL(k_router, dim3(T_TOK / 256), dim3(256), 0, stream,
                       x, rw, rb, eidx, sumprob);
    hipLaunchKernelGGL(k_scan, dim3(NE), dim3(256), 0, stream,
                       eidx, token_slot, s2t, counts);
    hipLaunchKernelGGL(k_lb, dim3(1), dim3(64), 0, stream,
                       counts, sumprob, out + (size_t)T_TOK * DM);
    hipLaunchKernelGGL(k_gather, dim3(NE * RP), dim3(256), 0, stream, x, s2t, xb);
    hipLaunchKernelGGL((k_gemm<4, 4, true, unsigned short>),
                       dim3(DFF / 128, RP / 128, NE), dim3(256), 0, stream,
                       xb, w1, b1, h, DM, DFF);
    hipLaunchKernelGGL((k_gemm<4, 2, false, float>),
                       dim3(DM / 64, RP / 128, NE), dim3(256), 0, stream,
                       h, w2, b2, y, DFF, DM);
    hipLaunchKernelGGL(k_scatter, dim3(T_TOK), dim3(256), 0, stream,
                       y, token_slot, out);
}